// Round 7
// baseline (467.297 us; speedup 1.0000x reference)
//
#include <hip/hip_runtime.h>
#include <math.h>

constexpr int D = 64;      // input / output feature dim
constexpr int H = 128;     // GRU hidden dim
constexpr int MAXLEN = 512;
constexpr int MSEQ = 8;    // sequences per block (duplicated across lane halves)

typedef __attribute__((ext_vector_type(8))) short short8;  // 8 bf16 = 4 VGPRs
typedef __attribute__((ext_vector_type(4))) float f32x4;   // MFMA accumulator

__device__ __forceinline__ short f2bf(float f) {           // f32 -> bf16 RNE (weight packs)
    unsigned u = __float_as_uint(f);
    u += 0x7fffu + ((u >> 16) & 1u);
    return (short)(u >> 16);
}
// HW packed convert: 2 x f32 -> 2 x bf16 (RNE), single VALU instr
__device__ __forceinline__ unsigned cvtpk(float a, float b) {
    unsigned r;
    asm volatile("v_cvt_pk_bf16_f32 %0, %1, %2" : "=v"(r) : "v"(a), "v"(b));
    return r;
}
__device__ __forceinline__ short8 pack8(float4 a, float4 b) {
    short8 r;
    r[0]=f2bf(a.x); r[1]=f2bf(a.y); r[2]=f2bf(a.z); r[3]=f2bf(a.w);
    r[4]=f2bf(b.x); r[5]=f2bf(b.y); r[6]=f2bf(b.z); r[7]=f2bf(b.w);
    return r;
}
__device__ __forceinline__ short8 cvt8(float4 a, float4 b) {   // 4 cvt_pk
    union { unsigned u[4]; short8 s; } r;
    r.u[0] = cvtpk(a.x, a.y); r.u[1] = cvtpk(a.z, a.w);
    r.u[2] = cvtpk(b.x, b.y); r.u[3] = cvtpk(b.z, b.w);
    return r.s;
}
__device__ __forceinline__ float rcp_(float x) { return __builtin_amdgcn_rcpf(x); }
__device__ __forceinline__ float sig_(float v) { return rcp_(1.0f + __expf(-v)); }
// tanh(v) = 2*sigmoid(2v) - 1; saturates correctly at +/-inf, 2 trans ops
__device__ __forceinline__ float tanh_(float v) {
    return fmaf(2.0f, rcp_(1.0f + __expf(-2.0f * v)), -1.0f);
}

// lgkm-only barrier: orders LDS producer->consumer without draining vmcnt --
// global x prefetches stay in flight across the barrier.
__device__ __forceinline__ void lgkm_barrier() {
    asm volatile("s_waitcnt lgkmcnt(0)\n\ts_barrier" ::: "memory");
}

#define MFMA(a,b,c) __builtin_amdgcn_mfma_f32_16x16x32_bf16((a),(b),(c),0,0,0)

// 512 threads = 8 waves, 2/SIMD. Swapped operands: gates^T[384,16] = W.state^T.
// MSEQ=8: N-cols s and s+8 carry the SAME seq (sq=s&7); after MFMA each lane
// handles only 2 features (j0 = (s>=8)?2:0) selected via cndmask -> gate
// trans/VALU halves vs MSEQ=16. x is loaded per-lane DIRECTLY from global
// (contiguous 8-float slices; L1 dedups the 8-way wave redundancy) -> no x
// staging in LDS; only h round-trips through (swizzled, double-buffered) LDS.
__global__ __launch_bounds__(512, 2)
void gru_mfma8s(const float* __restrict__ x,
                const int* __restrict__ offsets,   // int32 (JAX x64 disabled)
                const float* __restrict__ W_ih,
                const float* __restrict__ W_hh,
                const float* __restrict__ W_dense,
                const float* __restrict__ b_dense,
                float* __restrict__ out,
                int B, int T)
{
    const int bb  = blockIdx.x;
    const int tid = threadIdx.x;      // 0..511
    const int w   = tid >> 6;         // wave 0..7
    const int l   = tid & 63;
    const int s   = l & 15;           // MFMA m/n index 0..15
    const int q   = l >> 4;           // k-group 0..3
    const int sq  = s & 7;            // sequence within block
    const bool hi = (s >= 8);         // which feature pair this lane finishes

    __shared__ __align__(16) short h_bf[2][MSEQ * H];   // 2 x 2KB, row 256B, 16B-chunk XOR swizzle
    __shared__ int slen[MSEQ], sstart[MSEQ];
    __shared__ float h_f32[MSEQ][H];

    // ---- sequence bounds ----
    if (tid < MSEQ) {
        int sg = bb * MSEQ + tid;
        int st = 0, en = 1;
        if (sg < B) { st = offsets[sg]; en = (sg + 1 < B) ? offsets[sg + 1] : T; }
        int ln = en - st;
        ln = max(1, min(ln, MAXLEN));
        sstart[tid] = st; slen[tid] = ln;
    }
    ((int*)h_bf[0])[tid] = 0;         // zero h buffer 0 (512 dwords)
    __syncthreads();

    int nt = 1;
#pragma unroll
    for (int i = 0; i < MSEQ; ++i) nt = max(nt, slen[i]);

    // ---- A-frags: weight rows in registers (one-time). Row = g*H + w*16 + s ----
    short8 Wh[3][4];   // [gate][kt], K=128
    short8 Wi[3][2];   // [gate][kt], K=64
#pragma unroll
    for (int g = 0; g < 3; ++g) {
        const int grow = g * H + w * 16 + s;
        const float* ph = W_hh + (size_t)grow * H + q * 8;
#pragma unroll
        for (int kt = 0; kt < 4; ++kt)
            Wh[g][kt] = pack8(*(const float4*)(ph + kt * 32),
                              *(const float4*)(ph + kt * 32 + 4));
        const float* pi = W_ih + (size_t)grow * D + q * 8;
#pragma unroll
        for (int kt = 0; kt < 2; ++kt)
            Wi[g][kt] = pack8(*(const float4*)(pi + kt * 32),
                              *(const float4*)(pi + kt * 32 + 4));
    }

    // ---- LDS offsets (16B-chunk XOR swizzle by row sq) ----
    int hoff[4];
#pragma unroll
    for (int kt = 0; kt < 4; ++kt) hoff[kt] = sq * 256 + (((kt * 4 + q) ^ sq) << 4);
    // write: 2 bf16 at feature f0 = w*16 + q*4 + j0  (b32, 2-lanes/bank max)
    const int woff = sq * 256 + ((((2 * w) + (q >> 1)) ^ sq) << 4)
                   + ((q & 1) << 3) + (hi ? 4 : 0);

    // ---- per-lane x source: seq sq, k-slice q*8 (8 contiguous floats/kt) ----
    const int st_s = sstart[sq];
    const int ln_s = slen[sq];
    const float* xg = x + (size_t)st_s * D + q * 8;

    // preload x(0) -> current frags; x(1) -> raw regs
    short8 bxc[2];
    {
        float4 a0 = *(const float4*)(xg);
        float4 a1 = *(const float4*)(xg + 4);
        float4 a2 = *(const float4*)(xg + 32);
        float4 a3 = *(const float4*)(xg + 36);
        bxc[0] = cvt8(a0, a1); bxc[1] = cvt8(a2, a3);
    }
    const size_t r1 = (size_t)min(1, ln_s - 1) * D;
    float4 rb0 = *(const float4*)(xg + r1);
    float4 rb1 = *(const float4*)(xg + r1 + 4);
    float4 rb2 = *(const float4*)(xg + r1 + 32);
    float4 rb3 = *(const float4*)(xg + r1 + 36);

    float h0 = 0.f, h1 = 0.f;         // fp32 master state: 2 features/lane

    __syncthreads();                  // h_bf[0] visible

    for (int t = 0; t < nt; ++t) {
        const int p = t & 1;
        const char* hb = (const char*)h_bf[p];

        short8 bh[4];
#pragma unroll
        for (int kt = 0; kt < 4; ++kt) bh[kt] = *(const short8*)(hb + hoff[kt]);

        // issue x(t+2) prefetch (consumed 2 steps later; never drained)
        const size_t rn = (size_t)((t + 2 < ln_s) ? t + 2 : ln_s - 1) * D;
        float4 rc0 = *(const float4*)(xg + rn);
        float4 rc1 = *(const float4*)(xg + rn + 4);
        float4 rc2 = *(const float4*)(xg + rn + 32);
        float4 rc3 = *(const float4*)(xg + rn + 36);

        // 18 MFMAs: gates^T = W . state^T  (4 independent chains)
        f32x4 cr = {0,0,0,0}, cz = {0,0,0,0}, ci = {0,0,0,0}, chh = {0,0,0,0};
#pragma unroll
        for (int kt = 0; kt < 2; ++kt) {
            cr = MFMA(Wi[0][kt], bxc[kt], cr);
            cz = MFMA(Wi[1][kt], bxc[kt], cz);
            ci = MFMA(Wi[2][kt], bxc[kt], ci);
        }
#pragma unroll
        for (int kt = 0; kt < 4; ++kt) {
            cr  = MFMA(Wh[0][kt], bh[kt], cr);
            cz  = MFMA(Wh[1][kt], bh[kt], cz);
            chh = MFMA(Wh[2][kt], bh[kt], chh);
        }

        // select this lane's 2 features (cndmask, no divergence), gate math
        {
            float vr0 = hi ? cr[2]  : cr[0],  vr1 = hi ? cr[3]  : cr[1];
            float vz0 = hi ? cz[2]  : cz[0],  vz1 = hi ? cz[3]  : cz[1];
            float vi0 = hi ? ci[2]  : ci[0],  vi1 = hi ? ci[3]  : ci[1];
            float vh0 = hi ? chh[2] : chh[0], vh1 = hi ? chh[3] : chh[1];
            float r0 = sig_(vr0), r1 = sig_(vr1);
            float z0 = sig_(vz0), z1 = sig_(vz1);
            float n0 = tanh_(vi0 + r0 * vh0);
            float n1 = tanh_(vi1 + r1 * vh1);
            float hn0 = (1.0f - z0) * n0 + z0 * h0;
            float hn1 = (1.0f - z1) * n1 + z1 * h1;
            const bool upd = (t < ln_s);
            h0 = upd ? hn0 : h0;
            h1 = upd ? hn1 : h1;
        }

        // publish h' (single b32) into buffer p^1
        *(unsigned*)((char*)h_bf[p ^ 1] + woff) = cvtpk(h0, h1);

        // build next step's x frags from rb (1 step of vmcnt slack); rotate
        bxc[0] = cvt8(rb0, rb1); bxc[1] = cvt8(rb2, rb3);
        rb0 = rc0; rb1 = rc1; rb2 = rc2; rb3 = rc3;

        lgkm_barrier();    // LDS-only drain; x prefetch stays in flight
    }

    // ---- epilogue: h -> LDS fp32 (each lane owns 2 contiguous features) ----
    {
        float2 hv = { h0, h1 };
        *(float2*)&h_f32[sq][w * 16 + q * 4 + (hi ? 2 : 0)] = hv;
    }
    __syncthreads();

    // dense(128->64) + L2 normalize: wave = seq, lane = output col
    {
        const int s2 = tid >> 6;      // seq 0..7
        const int cb = tid & 63;      // col 0..63
        float acc = b_dense[cb];
        const float* wd = W_dense + (size_t)cb * H;
        float a0=0.f,a1=0.f,a2=0.f,a3=0.f;
#pragma unroll
        for (int j = 0; j < H; j += 4) {
            float4 hv = *(const float4*)&h_f32[s2][j];   // wave-uniform broadcast
            float4 wv = *(const float4*)(wd + j);
            a0 += hv.x*wv.x; a1 += hv.y*wv.y; a2 += hv.z*wv.z; a3 += hv.w*wv.w;
        }
        acc += (a0 + a1) + (a2 + a3);
        float s2q = acc * acc;
#pragma unroll
        for (int off = 32; off >= 1; off >>= 1) s2q += __shfl_xor(s2q, off);
        float invn = 1.0f / fmaxf(sqrtf(s2q), 1e-12f);
        int sg = bb * MSEQ + s2;
        if (sg < B) out[(size_t)sg * D + cb] = acc * invn;
    }
}

extern "C" void kernel_launch(void* const* d_in, const int* in_sizes, int n_in,
                              void* d_out, int out_size, void* d_ws, size_t ws_size,
                              hipStream_t stream) {
    const float* x       = (const float*)d_in[0];
    const int*   offsets = (const int*)d_in[1];
    const float* W_ih    = (const float*)d_in[2];
    const float* W_hh    = (const float*)d_in[3];
    const float* W_dense = (const float*)d_in[4];
    const float* b_dense = (const float*)d_in[5];
    float*       out     = (float*)d_out;

    const int B = in_sizes[1];
    const int T = in_sizes[0] / D;
    const int grid = (B + MSEQ - 1) / MSEQ;

    gru_mfma8s<<<grid, 512, 0, stream>>>(x, offsets, W_ih, W_hh, W_dense, b_dense, out, B, T);
}

// Round 10
// 349.376 us; speedup vs baseline: 1.3375x; 1.3375x over previous
//
#include <hip/hip_runtime.h>
#include <math.h>

constexpr int D = 64;      // input / output feature dim
constexpr int H = 128;     // GRU hidden dim
constexpr int MAXLEN = 512;
constexpr int MSEQ = 8;    // sequences per block (N-cols s and s+8 duplicate a seq)

typedef __attribute__((ext_vector_type(8))) short short8;  // 8 bf16 = 4 VGPRs
typedef __attribute__((ext_vector_type(4))) float f32x4;   // MFMA accumulator

__device__ __forceinline__ short f2bf(float f) {           // f32 -> bf16 RNE (weight packs)
    unsigned u = __float_as_uint(f);
    u += 0x7fffu + ((u >> 16) & 1u);
    return (short)(u >> 16);
}
// HW packed convert: 2 x f32 -> 2 x bf16 (RNE), single VALU instr
__device__ __forceinline__ unsigned cvtpk(float a, float b) {
    unsigned r;
    asm volatile("v_cvt_pk_bf16_f32 %0, %1, %2" : "=v"(r) : "v"(a), "v"(b));
    return r;
}
__device__ __forceinline__ short8 pack8(float4 a, float4 b) {
    short8 r;
    r[0]=f2bf(a.x); r[1]=f2bf(a.y); r[2]=f2bf(a.z); r[3]=f2bf(a.w);
    r[4]=f2bf(b.x); r[5]=f2bf(b.y); r[6]=f2bf(b.z); r[7]=f2bf(b.w);
    return r;
}
__device__ __forceinline__ float rcp_(float x) { return __builtin_amdgcn_rcpf(x); }
__device__ __forceinline__ float sig_(float v) { return rcp_(1.0f + __expf(-v)); }
__device__ __forceinline__ float tanh_(float v) {          // round-6 verified form
    float a = fabsf(v);
    float e = __expf(2.0f * a);
    float t = 1.0f - 2.0f * rcp_(e + 1.0f);
    return copysignf(t, v);
}
// lgkm-only barrier: orders LDS producer->consumer without draining vmcnt;
// global x prefetches stay in flight across the barrier (T4 pattern).
__device__ __forceinline__ void lgkm_barrier() {
    asm volatile("s_waitcnt lgkmcnt(0)\n\ts_barrier" ::: "memory");
}

#define MFMA(a,b,c) __builtin_amdgcn_mfma_f32_16x16x32_bf16((a),(b),(c),0,0,0)

// 512 threads = 8 waves, 2/SIMD. Swapped operands: gates^T[384,16] = W.state^T.
// MSEQ=8: N-cols s and s+8 carry the SAME seq (sq=s&7) -> h ds_reads are 2-way
// same-address broadcast (free), and each lane finishes only 2 features
// (selected via cndmask by hsel=s>>3) -> gate VALU/transcendentals halved.
// x is staged through XOR-swizzled double-buffered LDS (round-6 verified path;
// wave w stages seq-row w with lanes 0..31 -> balanced). h: fp32 master state
// in registers; bf16 XOR-swizzled double-buffered LDS carries it between
// steps. One lgkm-only barrier per step.
__global__ __launch_bounds__(512, 2)
void gru_m8(const float* __restrict__ x,
            const int* __restrict__ offsets,   // int32 (JAX x64 disabled)
            const float* __restrict__ W_ih,
            const float* __restrict__ W_hh,
            const float* __restrict__ W_dense,
            const float* __restrict__ b_dense,
            float* __restrict__ out,
            int B, int T)
{
    const int bb   = blockIdx.x;
    const int tid  = threadIdx.x;     // 0..511
    const int w    = tid >> 6;        // wave 0..7
    const int l    = tid & 63;
    const int s    = l & 15;          // MFMA m/n index
    const int q    = l >> 4;          // k-group 0..3
    const int sq   = s & 7;           // sequence within block
    const int hsel = s >> 3;          // 0/1: which feature pair this lane owns

    __shared__ __align__(16) short h_bf[2][MSEQ * H];   // 2 x 2KB, row 256B, 16B-chunk XOR swizzle
    __shared__ __align__(16) short x_bf[2][MSEQ * D];   // 2 x 1KB, row 128B, same swizzle
    __shared__ int slen[MSEQ], sstart[MSEQ];
    __shared__ float h_f32[MSEQ][H];

    // ---- sequence bounds ----
    if (tid < MSEQ) {
        int sg = bb * MSEQ + tid;
        int st = 0, en = 1;
        if (sg < B) { st = offsets[sg]; en = (sg + 1 < B) ? offsets[sg + 1] : T; }
        int ln = en - st;
        ln = max(1, min(ln, MAXLEN));
        sstart[tid] = st; slen[tid] = ln;
    }
    ((int*)h_bf[0])[tid] = 0;         // zero h buffer 0 (512 dwords)
    __syncthreads();

    int nt = 1;
#pragma unroll
    for (int i = 0; i < MSEQ; ++i) nt = max(nt, slen[i]);

    // ---- A-frags: weight rows in registers (one-time). Row = g*H + w*16 + s ----
    short8 Wh[3][4];   // [gate][kt], K=128
    short8 Wi[3][2];   // [gate][kt], K=64
#pragma unroll
    for (int g = 0; g < 3; ++g) {
        const int grow = g * H + w * 16 + s;
        const float* ph = W_hh + (size_t)grow * H + q * 8;
#pragma unroll
        for (int kt = 0; kt < 4; ++kt)
            Wh[g][kt] = pack8(*(const float4*)(ph + kt * 32),
                              *(const float4*)(ph + kt * 32 + 4));
        const float* pi = W_ih + (size_t)grow * D + q * 8;
#pragma unroll
        for (int kt = 0; kt < 2; ++kt)
            Wi[g][kt] = pack8(*(const float4*)(pi + kt * 32),
                              *(const float4*)(pi + kt * 32 + 4));
    }

    // ---- per-lane LDS byte offsets (16B-chunk XOR swizzle keyed by row sq) ----
    int hoff[4], xoff[2];
#pragma unroll
    for (int kt = 0; kt < 4; ++kt) hoff[kt] = sq * 256 + (((kt * 4 + q) ^ sq) << 4);
#pragma unroll
    for (int kt = 0; kt < 2; ++kt) xoff[kt] = sq * 128 + (((kt * 4 + q) ^ sq) << 4);
    // h write: 1 dword = 2 bf16 at feature f0 = w*16 + q*4 + 2*hsel, row sq
    const int woff = sq * 256 + ((((2 * w) + (q >> 1)) ^ sq) << 4)
                   + ((q & 1) << 3) + (hsel << 2);

    // ---- x staging: wave w serves seq-row w, lanes 0..31 (one float2 each) ----
    const bool xact = (l < 32);
    const int  pxx  = l & 31;         // float2 index within row
    const int  st_x = sstart[w];
    const int  ln_x = slen[w];
    const float* xg = x + (size_t)st_x * D + pxx * 2;
    const int xwoff = w * 128 + ((((pxx >> 2) ^ w) << 4)) + ((pxx & 3) << 2);

    if (xact) {   // stage x row 0 into buf 0
        float2 v = *(const float2*)xg;
        *(unsigned*)((char*)x_bf[0] + xwoff) = cvtpk(v.x, v.y);
    }
    float2 xpf = {0.f, 0.f};
    if (xact) xpf = *(const float2*)(xg + (size_t)min(1, ln_x - 1) * D);

    const int ln_s = slen[sq];
    float h0 = 0.f, h1 = 0.f;         // fp32 master state: 2 features/lane

    __syncthreads();                  // x_bf[0], h_bf[0] visible

    for (int t = 0; t < nt; ++t) {
        const int p = t & 1;
        const char* hb = (const char*)h_bf[p];
        const char* xb = (const char*)x_bf[p];

        short8 bh[4], bx[2];
#pragma unroll
        for (int kt = 0; kt < 4; ++kt) bh[kt] = *(const short8*)(hb + hoff[kt]);
#pragma unroll
        for (int kt = 0; kt < 2; ++kt) bx[kt] = *(const short8*)(xb + xoff[kt]);

        // issue x(t+2) prefetch (consumed next step's staging; never drained)
        float2 xnew = {0.f, 0.f};
        if (xact) {
            const int tn = (t + 2 < ln_x) ? t + 2 : ln_x - 1;
            xnew = *(const float2*)(xg + (size_t)tn * D);
        }

        // 18 MFMAs: gates^T = W . state^T  (4 independent chains)
        f32x4 cr = {0,0,0,0}, cz = {0,0,0,0}, ci = {0,0,0,0}, chh = {0,0,0,0};
#pragma unroll
        for (int kt = 0; kt < 2; ++kt) {
            cr = MFMA(Wi[0][kt], bx[kt], cr);
            cz = MFMA(Wi[1][kt], bx[kt], cz);
            ci = MFMA(Wi[2][kt], bx[kt], ci);
        }
#pragma unroll
        for (int kt = 0; kt < 4; ++kt) {
            cr  = MFMA(Wh[0][kt], bh[kt], cr);
            cz  = MFMA(Wh[1][kt], bh[kt], cz);
            chh = MFMA(Wh[2][kt], bh[kt], chh);
        }

        // gate math on this lane's 2 features (cndmask select, no branch)
        {
            float vr0 = hsel ? cr[2]  : cr[0],  vr1 = hsel ? cr[3]  : cr[1];
            float vz0 = hsel ? cz[2]  : cz[0],  vz1 = hsel ? cz[3]  : cz[1];
            float vi0 = hsel ? ci[2]  : ci[0],  vi1 = hsel ? ci[3]  : ci[1];
            float vh0 = hsel ? chh[2] : chh[0], vh1 = hsel ? chh[3] : chh[1];
            float r0 = sig_(vr0), r1 = sig_(vr1);
            float z0 = sig_(vz0), z1 = sig_(vz1);
            float n0 = tanh_(vi0 + r0 * vh0);
            float n1 = tanh_(vi1 + r1 * vh1);
            float hn0 = (1.0f - z0) * n0 + z0 * h0;
            float hn1 = (1.0f - z1) * n1 + z1 * h1;
            const bool upd = (t < ln_s);
            h0 = upd ? hn0 : h0;
            h1 = upd ? hn1 : h1;
        }

        // publish h' (single b32) + stage x(t+1) into buffer p^1
        *(unsigned*)((char*)h_bf[p ^ 1] + woff) = cvtpk(h0, h1);
        if (xact)
            *(unsigned*)((char*)x_bf[p ^ 1] + xwoff) = cvtpk(xpf.x, xpf.y);
        xpf = xnew;       // rotate prefetch register

        lgkm_barrier();   // LDS-only drain; x prefetch stays in flight
    }

    // ---- epilogue: h -> LDS fp32 (lane owns 2 contiguous features) ----
    {
        float2 hv = { h0, h1 };
        *(float2*)&h_f32[sq][w * 16 + q * 4 + 2 * hsel] = hv;
    }
    __syncthreads();

    // dense(128->64) + L2 normalize: wave = seq, lane = output col
    {
        const int s2 = tid >> 6;      // seq 0..7
        const int cb = tid & 63;      // col 0..63
        float acc = b_dense[cb];
        const float* wd = W_dense + (size_t)cb * H;
        float a0=0.f,a1=0.f,a2=0.f,a3=0.f;
#pragma unroll
        for (int j = 0; j < H; j += 4) {
            float4 hv = *(const float4*)&h_f32[s2][j];   // wave-uniform broadcast
            float4 wv = *(const float4*)(wd + j);
            a0 += hv.x*wv.x; a1 += hv.y*wv.y; a2 += hv.z*wv.z; a3 += hv.w*wv.w;
        }
        acc += (a0 + a1) + (a2 + a3);
        float s2q = acc * acc;
#pragma unroll
        for (int off = 32; off >= 1; off >>= 1) s2q += __shfl_xor(s2q, off);
        float invn = 1.0f / fmaxf(sqrtf(s2q), 1e-12f);
        int sg = bb * MSEQ + s2;
        if (sg < B) out[(size_t)sg * D + cb] = acc * invn;
    }
}

extern "C" void kernel_launch(void* const* d_in, const int* in_sizes, int n_in,
                              void* d_out, int out_size, void* d_ws, size_t ws_size,
                              hipStream_t stream) {
    const float* x       = (const float*)d_in[0];
    const int*   offsets = (const int*)d_in[1];
    const float* W_ih    = (const float*)d_in[2];
    const float* W_hh    = (const float*)d_in[3];
    const float* W_dense = (const float*)d_in[4];
    const float* b_dense = (const float*)d_in[5];
    float*       out     = (float*)d_out;

    const int B = in_sizes[1];
    const int T = in_sizes[0] / D;
    const int grid = (B + MSEQ - 1) / MSEQ;

    gru_m8<<<grid, 512, 0, stream>>>(x, offsets, W_ih, W_hh, W_dense, b_dense, out, B, T);
}